// Round 1
// 350.625 us; speedup vs baseline: 1.1549x; 1.1549x over previous
//
#include <hip/hip_runtime.h>

#define NUM_USER 200000
#define NUM_EVENT 50000
#define NUM_EDGES 1000000
#define DDIM 64
#define LDP 68  // LDS leading dim for linear tiles

// Bucketed CSR build: user buckets span 2048 nodes, event buckets span 256.
#define NBU 98                 // 98*2048 = 200704 >= NUM_USER
#define NBE 196                // 196*256 = 50176 >= NUM_EVENT
#define NB (NBU + NBE)         // 294
#define CHUNK 8192
#define NCH ((NUM_EDGES + CHUNK - 1) / CHUNK)  // 123

// Fused-linear grid split (balanced: 3125/1024 ~= 782/256 tiles per block)
#define LGU 1024
#define LGE 256
// Gather: persistent grid, phase-sequential (all waves do users, then events)
#define GGRID 2048

// bf16 pair packing: lin tables stored as uint = (bf16(hi)<<16)|bf16(lo).
__device__ __forceinline__ unsigned int pack_bf2(float lo, float hi) {
  unsigned int ul = __float_as_uint(lo);
  unsigned int uh = __float_as_uint(hi);
  ul = (ul + 0x7FFFu + ((ul >> 16) & 1u)) >> 16;
  uh = (uh + 0x7FFFu + ((uh >> 16) & 1u)) & 0xFFFF0000u;
  return uh | ul;
}
__device__ __forceinline__ float bf_lo(unsigned int v) { return __uint_as_float(v << 16); }
__device__ __forceinline__ float bf_hi(unsigned int v) { return __uint_as_float(v & 0xFFFF0000u); }

// ---------------- CSR build: pass A (bucket histogram) ----------------

__global__ __launch_bounds__(256) void bucket_count_kernel(
    const int* __restrict__ src, const int* __restrict__ dst,
    int* __restrict__ bc) {
  __shared__ int cnt[NB];
  for (int i = threadIdx.x; i < NB; i += 256) cnt[i] = 0;
  __syncthreads();
  const int e0 = blockIdx.x * CHUNK;
  const int e1 = min(e0 + CHUNK, NUM_EDGES);
  for (int i = e0 + threadIdx.x; i < e1; i += 256) {
    atomicAdd(&cnt[dst[i] >> 11], 1);
    atomicAdd(&cnt[NBU + (src[i] >> 8)], 1);
  }
  __syncthreads();
  for (int i = threadIdx.x; i < NB; i += 256)
    if (cnt[i]) atomicAdd(&bc[i], cnt[i]);
}

__global__ __launch_bounds__(512) void bucket_scan_kernel(
    const int* __restrict__ bc, int* __restrict__ bbase, int* __restrict__ gcur) {
  __shared__ int s[512];
  const int tid = threadIdx.x;
  int v = (tid < NB) ? bc[tid] : 0;
  s[tid] = v;
  __syncthreads();
  for (int off = 1; off < 512; off <<= 1) {
    int t = (tid >= off) ? s[tid - off] : 0;
    __syncthreads();
    s[tid] += t;
    __syncthreads();
  }
  if (tid < NB) {
    int excl = s[tid] - v;
    bbase[tid] = excl;
    gcur[tid] = excl - ((tid >= NBU) ? NUM_EDGES : 0);
  }
  if (tid == 0) bbase[NB] = 2 * NUM_EDGES;
}

// Pass A2: scatter packed items into bucket-contiguous runs.
// itemU = (dst&2047)<<16 | src ; itemE = (src&255)<<18 | dst
__global__ __launch_bounds__(256) void bucket_scatter_kernel(
    const int* __restrict__ src, const int* __restrict__ dst,
    int* __restrict__ gcur, unsigned int* __restrict__ itemsU,
    unsigned int* __restrict__ itemsE) {
  __shared__ int cnt[NB];
  __shared__ int cur[NB];
  for (int i = threadIdx.x; i < NB; i += 256) cnt[i] = 0;
  __syncthreads();
  const int e0 = blockIdx.x * CHUNK;
  const int e1 = min(e0 + CHUNK, NUM_EDGES);
  for (int i = e0 + threadIdx.x; i < e1; i += 256) {
    atomicAdd(&cnt[dst[i] >> 11], 1);
    atomicAdd(&cnt[NBU + (src[i] >> 8)], 1);
  }
  __syncthreads();
  for (int i = threadIdx.x; i < NB; i += 256) {
    int c = cnt[i];
    cur[i] = c ? atomicAdd(&gcur[i], c) : 0;
  }
  __syncthreads();
  for (int i = e0 + threadIdx.x; i < e1; i += 256) {
    const int s = src[i];
    const int d = dst[i];
    int r = atomicAdd(&cur[d >> 11], 1);
    itemsU[r] = ((unsigned int)(d & 2047) << 16) | (unsigned int)s;
    int r2 = atomicAdd(&cur[NBU + (s >> 8)], 1);
    itemsE[r2] = ((unsigned int)(s & 255) << 18) | (unsigned int)d;
  }
}

// ---------------- Pass B bodies (share a union'd LDS buffer) ----------------

// user: one block per bucket of 2048 users. smem needs 2048+256 ints = 9216 B.
__device__ __forceinline__ void build_user_body(
    unsigned char* smem, const int* __restrict__ bbase,
    const unsigned int* __restrict__ itemsU, int* __restrict__ offs,
    unsigned short* __restrict__ lists_u, int b) {
  int* cnt = (int*)smem;       // 2048
  int* part = cnt + 2048;      // 256
  const int istart = bbase[b];
  const int iend = bbase[b + 1];
  const int tid = threadIdx.x;
  for (int i = tid; i < 2048; i += 256) cnt[i] = 0;
  __syncthreads();
  for (int i = istart + tid; i < iend; i += 256)
    atomicAdd(&cnt[itemsU[i] >> 16], 1);
  __syncthreads();
  int v[8];
  int sum = 0;
#pragma unroll
  for (int j = 0; j < 8; ++j) {
    v[j] = cnt[tid * 8 + j];
    sum += v[j];
  }
  part[tid] = sum;
  __syncthreads();
  for (int off = 1; off < 256; off <<= 1) {
    int t = (tid >= off) ? part[tid - off] : 0;
    __syncthreads();
    part[tid] += t;
    __syncthreads();
  }
  int run = (tid == 0) ? 0 : part[tid - 1];
  const int node0 = b * 2048;
#pragma unroll
  for (int j = 0; j < 8; ++j) {
    const int n = node0 + tid * 8 + j;
    if (n < NUM_USER) offs[n] = istart + run + v[j];  // END position
    cnt[tid * 8 + j] = run;                           // exclusive -> cursor
    run += v[j];
  }
  __syncthreads();
  for (int i = istart + tid; i < iend; i += 256) {
    const unsigned int it = itemsU[i];
    int r = atomicAdd(&cnt[it >> 16], 1);
    lists_u[istart + r] = (unsigned short)(it & 0xFFFFu);
  }
}

// event: one block per bucket of 256 events. smem needs 512 ints = 2048 B.
__device__ __forceinline__ void build_event_body(
    unsigned char* smem, const int* __restrict__ bbase,
    const unsigned int* __restrict__ itemsE, int* __restrict__ offs,
    int* __restrict__ lists_e, int b) {
  int* cnt = (int*)smem;   // 256
  int* s2 = cnt + 256;     // 256
  const int istart = bbase[NBU + b] - NUM_EDGES;
  const int iend = bbase[NBU + b + 1] - NUM_EDGES;
  const int tid = threadIdx.x;
  cnt[tid] = 0;
  __syncthreads();
  for (int i = istart + tid; i < iend; i += 256)
    atomicAdd(&cnt[itemsE[i] >> 18], 1);
  __syncthreads();
  const int v = cnt[tid];
  s2[tid] = v;
  __syncthreads();
  for (int off = 1; off < 256; off <<= 1) {
    int t = (tid >= off) ? s2[tid - off] : 0;
    __syncthreads();
    s2[tid] += t;
    __syncthreads();
  }
  const int excl = s2[tid] - v;
  const int e0 = b * 256;
  if (e0 + tid < NUM_EVENT)
    offs[NUM_USER + e0 + tid] = NUM_EDGES + istart + excl + v;  // END position
  cnt[tid] = excl;
  __syncthreads();
  for (int i = istart + tid; i < iend; i += 256) {
    const unsigned int it = itemsE[i];
    int r = atomicAdd(&cnt[it >> 18], 1);
    lists_e[istart + r] = (int)(it & 0x3FFFFu);
  }
}

// ---------------- Fused linear: y = x @ W^T + b, fp32 in, bf16-packed out ----------------
// smem needs 2 * 64*LDP floats = 34816 B.

__device__ __forceinline__ void linear_tiles(
    unsigned char* smem, const float* __restrict__ x, const float* __restrict__ W,
    const float* __restrict__ b, unsigned int* __restrict__ y, int n,
    int ntiles, int bid, int nblocks) {
  float* xT = (float*)smem;       // xT[k][r]
  float* wT = xT + 64 * LDP;      // wT[k][c] = W[c][k]
  const int tid = threadIdx.x;
  const int r64 = tid & 63;
  const int q = tid >> 6;

  {  // Stage W^T once per block.
    const int c = r64;
    const float4* wr = reinterpret_cast<const float4*>(W + (size_t)c * DDIM);
#pragma unroll
    for (int i = 0; i < 4; ++i) {
      const int kc4 = q * 4 + i;
      float4 t = wr[kc4];
      wT[(kc4 * 4 + 0) * LDP + c] = t.x;
      wT[(kc4 * 4 + 1) * LDP + c] = t.y;
      wT[(kc4 * 4 + 2) * LDP + c] = t.z;
      wT[(kc4 * 4 + 3) * LDP + c] = t.w;
    }
  }

  const int cg = tid & 15;  // cols cg*4..cg*4+3
  const int rg = tid >> 4;  // rows rg*4..rg*4+3
  const float4 bv = reinterpret_cast<const float4*>(b)[cg];

  for (int tile = bid; tile < ntiles; tile += nblocks) {
    const int row0 = tile * 64;
    const int nrows = min(64, n - row0);
    __syncthreads();  // prior-iter readers done (also publishes W on first iter)
    {
      const int r = r64;
      if (r < nrows) {
        const float4* xr = reinterpret_cast<const float4*>(x + (size_t)(row0 + r) * DDIM);
#pragma unroll
        for (int i = 0; i < 4; ++i) {
          const int kc4 = q * 4 + i;
          float4 t = xr[kc4];
          xT[(kc4 * 4 + 0) * LDP + r] = t.x;
          xT[(kc4 * 4 + 1) * LDP + r] = t.y;
          xT[(kc4 * 4 + 2) * LDP + r] = t.z;
          xT[(kc4 * 4 + 3) * LDP + r] = t.w;
        }
      }
    }
    __syncthreads();

    float acc[4][4];
#pragma unroll
    for (int i = 0; i < 4; ++i) {
      acc[i][0] = bv.x; acc[i][1] = bv.y; acc[i][2] = bv.z; acc[i][3] = bv.w;
    }
#pragma unroll 8
    for (int k = 0; k < 64; ++k) {
      const float4 xv = *reinterpret_cast<const float4*>(&xT[k * LDP + rg * 4]);
      const float4 wv = *reinterpret_cast<const float4*>(&wT[k * LDP + cg * 4]);
      const float xa[4] = {xv.x, xv.y, xv.z, xv.w};
      const float wa[4] = {wv.x, wv.y, wv.z, wv.w};
#pragma unroll
      for (int i = 0; i < 4; ++i)
#pragma unroll
        for (int j = 0; j < 4; ++j) acc[i][j] += xa[i] * wa[j];
    }
#pragma unroll
    for (int i = 0; i < 4; ++i) {
      const int r = rg * 4 + i;
      if (r < nrows) {
        uint2 o = make_uint2(pack_bf2(acc[i][0], acc[i][1]),
                             pack_bf2(acc[i][2], acc[i][3]));
        reinterpret_cast<uint2*>(y + (size_t)(row0 + r) * 32)[cg] = o;
      }
    }
  }
}

// Merged dispatch: CSR pass-B (294 blocks) + layer-1 linear (1280 blocks).
// The build blocks leave >60% of CUs idle; linear-1 is independent of the CSR
// chain, so it fills them for free. Single union'd LDS buffer (34816 B).
__global__ __launch_bounds__(256) void build_lin_kernel(
    const int* __restrict__ bbase, const unsigned int* __restrict__ itemsU,
    const unsigned int* __restrict__ itemsE, int* __restrict__ offs,
    unsigned short* __restrict__ lists_u, int* __restrict__ lists_e,
    const float* __restrict__ xu, const float* __restrict__ Wu,
    const float* __restrict__ bu, unsigned int* __restrict__ yu,
    const float* __restrict__ xe, const float* __restrict__ We,
    const float* __restrict__ be, unsigned int* __restrict__ ye) {
  __shared__ __align__(16) unsigned char smem[64 * LDP * 2 * sizeof(float)];
  const int bx = blockIdx.x;
  if (bx < NBU) {
    build_user_body(smem, bbase, itemsU, offs, lists_u, bx);
  } else if (bx < NB) {
    build_event_body(smem, bbase, itemsE, offs, lists_e, bx - NBU);
  } else {
    const int bid = bx - NB;
    if (bid < LGU) {
      linear_tiles(smem, xu, Wu, bu, yu, NUM_USER, (NUM_USER + 63) / 64, bid, LGU);
    } else {
      linear_tiles(smem, xe, We, be, ye, NUM_EVENT, (NUM_EVENT + 63) / 64,
                   bid - LGU, LGE);
    }
  }
}

// Layer-2 linear (standalone, depends on gather-1 output).
__global__ __launch_bounds__(256) void linear_fused_kernel(
    const float* __restrict__ xu, const float* __restrict__ Wu,
    const float* __restrict__ bu, unsigned int* __restrict__ yu,
    const float* __restrict__ xe, const float* __restrict__ We,
    const float* __restrict__ be, unsigned int* __restrict__ ye) {
  __shared__ __align__(16) unsigned char smem[64 * LDP * 2 * sizeof(float)];
  if (blockIdx.x < LGU) {
    linear_tiles(smem, xu, Wu, bu, yu, NUM_USER, (NUM_USER + 63) / 64,
                 blockIdx.x, LGU);
  } else {
    linear_tiles(smem, xe, We, be, ye, NUM_EVENT, (NUM_EVENT + 63) / 64,
                 blockIdx.x - LGU, LGE);
  }
}

// ---------------- Fused gather aggregation (phase-sequential, prefetched) ----------------
// Quarter-wave (16 lanes) per node; lane dl holds dims 4dl..4dl+3 as one uint2.
// vs. the previous half-wave/u32 layout: 2x node streams per wave (4 instead of
// 2), each row-load instruction fetches 4 rows (512 B) instead of 2 (256 B),
// and an 8-deep unroll tier covers the degree~20 event phase. Same per-dim
// accumulation order -> bit-identical results.
template <typename IdxT>
__device__ __forceinline__ void gather_phase(
    const int* __restrict__ offs, const IdxT* __restrict__ lists,
    const uint2* __restrict__ lin_self, const uint2* __restrict__ lin_other,
    float4* __restrict__ out, int n, int obase, int lbase, int stream_id,
    int nstreams, int dl) {
  int node = stream_id;
  if (node >= n) return;
  int g = obase + node;
  int start = (g == 0) ? 0 : offs[g - 1];
  int end = offs[g];
  uint2 sv = lin_self[(size_t)node * 16 + dl];

  while (true) {
    // Prefetch next node's descriptors (issued before the gather chain).
    const int nnode = node + nstreams;
    int nstart = 0, nend = 0;
    uint2 nsv = make_uint2(0u, 0u);
    if (nnode < n) {
      const int ng = obase + nnode;
      nstart = offs[ng - 1];
      nend = offs[ng];
      nsv = lin_self[(size_t)nnode * 16 + dl];
    }

    float a0 = bf_lo(sv.x), a1 = bf_hi(sv.x);
    float a2 = bf_lo(sv.y), a3 = bf_hi(sv.y);
    int j = start;
    for (; j + 8 <= end; j += 8) {
      int o[8];
#pragma unroll
      for (int t = 0; t < 8; ++t) o[t] = (int)lists[j + t - lbase];
      uint2 v[8];
#pragma unroll
      for (int t = 0; t < 8; ++t) v[t] = lin_other[(size_t)o[t] * 16 + dl];
#pragma unroll
      for (int t = 0; t < 8; ++t) {
        a0 += bf_lo(v[t].x); a1 += bf_hi(v[t].x);
        a2 += bf_lo(v[t].y); a3 += bf_hi(v[t].y);
      }
    }
    for (; j + 4 <= end; j += 4) {
      int o[4];
#pragma unroll
      for (int t = 0; t < 4; ++t) o[t] = (int)lists[j + t - lbase];
      uint2 v[4];
#pragma unroll
      for (int t = 0; t < 4; ++t) v[t] = lin_other[(size_t)o[t] * 16 + dl];
#pragma unroll
      for (int t = 0; t < 4; ++t) {
        a0 += bf_lo(v[t].x); a1 += bf_hi(v[t].x);
        a2 += bf_lo(v[t].y); a3 += bf_hi(v[t].y);
      }
    }
    for (; j < end; ++j) {
      const int o0 = (int)lists[j - lbase];
      const uint2 v0 = lin_other[(size_t)o0 * 16 + dl];
      a0 += bf_lo(v0.x); a1 += bf_hi(v0.x);
      a2 += bf_lo(v0.y); a3 += bf_hi(v0.y);
    }
    const float inv = 1.0f / (float)(end - start + 1);
    out[(size_t)node * 16 + dl] =
        make_float4(a0 * inv, a1 * inv, a2 * inv, a3 * inv);

    if (nnode >= n) break;
    node = nnode;
    start = nstart;
    end = nend;
    sv = nsv;
  }
}

__global__ __launch_bounds__(256) void gather_fused_kernel(
    const int* __restrict__ offs, const unsigned short* __restrict__ lists_u,
    const int* __restrict__ lists_e, const unsigned int* __restrict__ lin_u,
    const unsigned int* __restrict__ lin_e, float* __restrict__ out_u,
    float* __restrict__ out_e) {
  const int lane = threadIdx.x & 63;
  const int dl = lane & 15;
  const int qw = ((blockIdx.x * (blockDim.x >> 6) + (threadIdx.x >> 6)) << 2) |
                 (lane >> 4);               // global quarter-wave id
  const int nstreams = GGRID * 16;          // 32768 streams, both phases
  gather_phase<unsigned short>(
      offs, lists_u, reinterpret_cast<const uint2*>(lin_u),
      reinterpret_cast<const uint2*>(lin_e), reinterpret_cast<float4*>(out_u),
      NUM_USER, 0, 0, qw, nstreams, dl);
  gather_phase<int>(
      offs, lists_e, reinterpret_cast<const uint2*>(lin_e),
      reinterpret_cast<const uint2*>(lin_u), reinterpret_cast<float4*>(out_e),
      NUM_EVENT, NUM_USER, NUM_EDGES, qw, nstreams, dl);
}

// ---------------- Launch ----------------

extern "C" void kernel_launch(void* const* d_in, const int* in_sizes, int n_in,
                              void* d_out, int out_size, void* d_ws,
                              size_t ws_size, hipStream_t stream) {
  const float* x_user = (const float*)d_in[0];
  const float* x_event = (const float*)d_in[1];
  const int* src = (const int*)d_in[2];
  const int* dst = (const int*)d_in[3];
  const float* Wu0 = (const float*)d_in[4];
  const float* bu0 = (const float*)d_in[5];
  const float* We0 = (const float*)d_in[6];
  const float* be0 = (const float*)d_in[7];
  const float* Wu1 = (const float*)d_in[8];
  const float* bu1 = (const float*)d_in[9];
  const float* We1 = (const float*)d_in[10];
  const float* be1 = (const float*)d_in[11];

  unsigned int* lin_u = (unsigned int*)d_ws;            // 6.4M u32
  unsigned int* lin_e = lin_u + (size_t)NUM_USER * 32;  // 1.6M u32
  int* offs = (int*)(lin_e + (size_t)NUM_EVENT * 32);   // 250,000
  int* bc = offs + (NUM_USER + NUM_EVENT);              // 294
  int* bbase = bc + NB;                                 // 295
  int* gcur = bbase + NB + 1;                           // 294
  unsigned int* itemsU = (unsigned int*)(gcur + NB);    // 1M
  unsigned int* itemsE = itemsU + NUM_EDGES;            // 1M
  int* lists_e = (int*)(itemsE + NUM_EDGES);            // 1M int
  unsigned short* lists_u = (unsigned short*)(lists_e + NUM_EDGES);  // 1M u16

  float* out_u = (float*)d_out;
  float* out_e = out_u + (size_t)NUM_USER * DDIM;

  // --- CSR build (bucketed counting sort; shared by both layers) ---
  hipMemsetAsync(bc, 0, NB * sizeof(int), stream);
  bucket_count_kernel<<<NCH, 256, 0, stream>>>(src, dst, bc);
  bucket_scan_kernel<<<1, 512, 0, stream>>>(bc, bbase, gcur);
  bucket_scatter_kernel<<<NCH, 256, 0, stream>>>(src, dst, gcur, itemsU, itemsE);

  // ---- CSR pass-B + Layer-1 linear (merged: independent work shares one grid) ----
  build_lin_kernel<<<NB + LGU + LGE, 256, 0, stream>>>(
      bbase, itemsU, itemsE, offs, lists_u, lists_e,
      x_user, Wu0, bu0, lin_u, x_event, We0, be0, lin_e);
  gather_fused_kernel<<<GGRID, 256, 0, stream>>>(
      offs, lists_u, lists_e, lin_u, lin_e, out_u, out_e);

  // ---- Layer 2 ----
  linear_fused_kernel<<<LGU + LGE, 256, 0, stream>>>(
      out_u, Wu1, bu1, lin_u, out_e, We1, be1, lin_e);
  gather_fused_kernel<<<GGRID, 256, 0, stream>>>(
      offs, lists_u, lists_e, lin_u, lin_e, out_u, out_e);
}

// Round 2
// 349.830 us; speedup vs baseline: 1.1575x; 1.0023x over previous
//
#include <hip/hip_runtime.h>

#define NUM_USER 200000
#define NUM_EVENT 50000
#define NUM_EDGES 1000000
#define DDIM 64
#define LDP 68  // LDS leading dim for linear tiles

// Bucketed CSR build: user buckets span 2048 nodes, event buckets span 256.
#define NBU 98                 // 98*2048 = 200704 >= NUM_USER
#define NBE 196                // 196*256 = 50176 >= NUM_EVENT
#define NB (NBU + NBE)         // 294
#define CHUNK 8192
#define NCH ((NUM_EDGES + CHUNK - 1) / CHUNK)  // 123

// Fused-linear grid split (balanced: 3125/1024 ~= 782/256 tiles per block)
#define LGU 1024
#define LGE 256
// Gather: persistent grid, phase-sequential (all waves do users, then events)
#define GGRID 2048

// bf16 pair packing: lin tables stored as uint = (bf16(hi)<<16)|bf16(lo).
__device__ __forceinline__ unsigned int pack_bf2(float lo, float hi) {
  unsigned int ul = __float_as_uint(lo);
  unsigned int uh = __float_as_uint(hi);
  ul = (ul + 0x7FFFu + ((ul >> 16) & 1u)) >> 16;
  uh = (uh + 0x7FFFu + ((uh >> 16) & 1u)) & 0xFFFF0000u;
  return uh | ul;
}
__device__ __forceinline__ float bf_lo(unsigned int v) { return __uint_as_float(v << 16); }
__device__ __forceinline__ float bf_hi(unsigned int v) { return __uint_as_float(v & 0xFFFF0000u); }

// ---------------- CSR build: pass A (bucket histogram) ----------------

__global__ __launch_bounds__(256) void bucket_count_kernel(
    const int* __restrict__ src, const int* __restrict__ dst,
    int* __restrict__ bc) {
  __shared__ int cnt[NB];
  for (int i = threadIdx.x; i < NB; i += 256) cnt[i] = 0;
  __syncthreads();
  const int e0 = blockIdx.x * CHUNK;
  const int e1 = min(e0 + CHUNK, NUM_EDGES);
  for (int i = e0 + threadIdx.x; i < e1; i += 256) {
    atomicAdd(&cnt[dst[i] >> 11], 1);
    atomicAdd(&cnt[NBU + (src[i] >> 8)], 1);
  }
  __syncthreads();
  for (int i = threadIdx.x; i < NB; i += 256)
    if (cnt[i]) atomicAdd(&bc[i], cnt[i]);
}

__global__ __launch_bounds__(512) void bucket_scan_kernel(
    const int* __restrict__ bc, int* __restrict__ bbase, int* __restrict__ gcur) {
  __shared__ int s[512];
  const int tid = threadIdx.x;
  int v = (tid < NB) ? bc[tid] : 0;
  s[tid] = v;
  __syncthreads();
  for (int off = 1; off < 512; off <<= 1) {
    int t = (tid >= off) ? s[tid - off] : 0;
    __syncthreads();
    s[tid] += t;
    __syncthreads();
  }
  if (tid < NB) {
    int excl = s[tid] - v;
    bbase[tid] = excl;
    gcur[tid] = excl - ((tid >= NBU) ? NUM_EDGES : 0);
  }
  if (tid == 0) bbase[NB] = 2 * NUM_EDGES;
}

// Pass A2: scatter packed items into bucket-contiguous runs.
// itemU = (dst&2047)<<16 | src ; itemE = (src&255)<<18 | dst
__global__ __launch_bounds__(256) void bucket_scatter_kernel(
    const int* __restrict__ src, const int* __restrict__ dst,
    int* __restrict__ gcur, unsigned int* __restrict__ itemsU,
    unsigned int* __restrict__ itemsE) {
  __shared__ int cnt[NB];
  __shared__ int cur[NB];
  for (int i = threadIdx.x; i < NB; i += 256) cnt[i] = 0;
  __syncthreads();
  const int e0 = blockIdx.x * CHUNK;
  const int e1 = min(e0 + CHUNK, NUM_EDGES);
  for (int i = e0 + threadIdx.x; i < e1; i += 256) {
    atomicAdd(&cnt[dst[i] >> 11], 1);
    atomicAdd(&cnt[NBU + (src[i] >> 8)], 1);
  }
  __syncthreads();
  for (int i = threadIdx.x; i < NB; i += 256) {
    int c = cnt[i];
    cur[i] = c ? atomicAdd(&gcur[i], c) : 0;
  }
  __syncthreads();
  for (int i = e0 + threadIdx.x; i < e1; i += 256) {
    const int s = src[i];
    const int d = dst[i];
    int r = atomicAdd(&cur[d >> 11], 1);
    itemsU[r] = ((unsigned int)(d & 2047) << 16) | (unsigned int)s;
    int r2 = atomicAdd(&cur[NBU + (s >> 8)], 1);
    itemsE[r2] = ((unsigned int)(s & 255) << 18) | (unsigned int)d;
  }
}

// ---------------- Pass B bodies (share a union'd LDS buffer) ----------------

// user: one block per bucket of 2048 users. smem needs 2048+256 ints = 9216 B.
__device__ __forceinline__ void build_user_body(
    unsigned char* smem, const int* __restrict__ bbase,
    const unsigned int* __restrict__ itemsU, int* __restrict__ offs,
    unsigned short* __restrict__ lists_u, int b) {
  int* cnt = (int*)smem;       // 2048
  int* part = cnt + 2048;      // 256
  const int istart = bbase[b];
  const int iend = bbase[b + 1];
  const int tid = threadIdx.x;
  for (int i = tid; i < 2048; i += 256) cnt[i] = 0;
  __syncthreads();
  for (int i = istart + tid; i < iend; i += 256)
    atomicAdd(&cnt[itemsU[i] >> 16], 1);
  __syncthreads();
  int v[8];
  int sum = 0;
#pragma unroll
  for (int j = 0; j < 8; ++j) {
    v[j] = cnt[tid * 8 + j];
    sum += v[j];
  }
  part[tid] = sum;
  __syncthreads();
  for (int off = 1; off < 256; off <<= 1) {
    int t = (tid >= off) ? part[tid - off] : 0;
    __syncthreads();
    part[tid] += t;
    __syncthreads();
  }
  int run = (tid == 0) ? 0 : part[tid - 1];
  const int node0 = b * 2048;
#pragma unroll
  for (int j = 0; j < 8; ++j) {
    const int n = node0 + tid * 8 + j;
    if (n < NUM_USER) offs[n] = istart + run + v[j];  // END position
    cnt[tid * 8 + j] = run;                           // exclusive -> cursor
    run += v[j];
  }
  __syncthreads();
  for (int i = istart + tid; i < iend; i += 256) {
    const unsigned int it = itemsU[i];
    int r = atomicAdd(&cnt[it >> 16], 1);
    lists_u[istart + r] = (unsigned short)(it & 0xFFFFu);
  }
}

// event: one block per bucket of 256 events. smem needs 512 ints = 2048 B.
__device__ __forceinline__ void build_event_body(
    unsigned char* smem, const int* __restrict__ bbase,
    const unsigned int* __restrict__ itemsE, int* __restrict__ offs,
    int* __restrict__ lists_e, int b) {
  int* cnt = (int*)smem;   // 256
  int* s2 = cnt + 256;     // 256
  const int istart = bbase[NBU + b] - NUM_EDGES;
  const int iend = bbase[NBU + b + 1] - NUM_EDGES;
  const int tid = threadIdx.x;
  cnt[tid] = 0;
  __syncthreads();
  for (int i = istart + tid; i < iend; i += 256)
    atomicAdd(&cnt[itemsE[i] >> 18], 1);
  __syncthreads();
  const int v = cnt[tid];
  s2[tid] = v;
  __syncthreads();
  for (int off = 1; off < 256; off <<= 1) {
    int t = (tid >= off) ? s2[tid - off] : 0;
    __syncthreads();
    s2[tid] += t;
    __syncthreads();
  }
  const int excl = s2[tid] - v;
  const int e0 = b * 256;
  if (e0 + tid < NUM_EVENT)
    offs[NUM_USER + e0 + tid] = NUM_EDGES + istart + excl + v;  // END position
  cnt[tid] = excl;
  __syncthreads();
  for (int i = istart + tid; i < iend; i += 256) {
    const unsigned int it = itemsE[i];
    int r = atomicAdd(&cnt[it >> 18], 1);
    lists_e[istart + r] = (int)(it & 0x3FFFFu);
  }
}

// ---------------- Fused linear: y = x @ W^T + b, fp32 in, bf16-packed out ----------------
// smem needs 2 * 64*LDP floats = 34816 B.

__device__ __forceinline__ void linear_tiles(
    unsigned char* smem, const float* __restrict__ x, const float* __restrict__ W,
    const float* __restrict__ b, unsigned int* __restrict__ y, int n,
    int ntiles, int bid, int nblocks) {
  float* xT = (float*)smem;       // xT[k][r]
  float* wT = xT + 64 * LDP;      // wT[k][c] = W[c][k]
  const int tid = threadIdx.x;
  const int r64 = tid & 63;
  const int q = tid >> 6;

  {  // Stage W^T once per block.
    const int c = r64;
    const float4* wr = reinterpret_cast<const float4*>(W + (size_t)c * DDIM);
#pragma unroll
    for (int i = 0; i < 4; ++i) {
      const int kc4 = q * 4 + i;
      float4 t = wr[kc4];
      wT[(kc4 * 4 + 0) * LDP + c] = t.x;
      wT[(kc4 * 4 + 1) * LDP + c] = t.y;
      wT[(kc4 * 4 + 2) * LDP + c] = t.z;
      wT[(kc4 * 4 + 3) * LDP + c] = t.w;
    }
  }

  const int cg = tid & 15;  // cols cg*4..cg*4+3
  const int rg = tid >> 4;  // rows rg*4..rg*4+3
  const float4 bv = reinterpret_cast<const float4*>(b)[cg];

  for (int tile = bid; tile < ntiles; tile += nblocks) {
    const int row0 = tile * 64;
    const int nrows = min(64, n - row0);
    __syncthreads();  // prior-iter readers done (also publishes W on first iter)
    {
      const int r = r64;
      if (r < nrows) {
        const float4* xr = reinterpret_cast<const float4*>(x + (size_t)(row0 + r) * DDIM);
#pragma unroll
        for (int i = 0; i < 4; ++i) {
          const int kc4 = q * 4 + i;
          float4 t = xr[kc4];
          xT[(kc4 * 4 + 0) * LDP + r] = t.x;
          xT[(kc4 * 4 + 1) * LDP + r] = t.y;
          xT[(kc4 * 4 + 2) * LDP + r] = t.z;
          xT[(kc4 * 4 + 3) * LDP + r] = t.w;
        }
      }
    }
    __syncthreads();

    float acc[4][4];
#pragma unroll
    for (int i = 0; i < 4; ++i) {
      acc[i][0] = bv.x; acc[i][1] = bv.y; acc[i][2] = bv.z; acc[i][3] = bv.w;
    }
#pragma unroll 8
    for (int k = 0; k < 64; ++k) {
      const float4 xv = *reinterpret_cast<const float4*>(&xT[k * LDP + rg * 4]);
      const float4 wv = *reinterpret_cast<const float4*>(&wT[k * LDP + cg * 4]);
      const float xa[4] = {xv.x, xv.y, xv.z, xv.w};
      const float wa[4] = {wv.x, wv.y, wv.z, wv.w};
#pragma unroll
      for (int i = 0; i < 4; ++i)
#pragma unroll
        for (int j = 0; j < 4; ++j) acc[i][j] += xa[i] * wa[j];
    }
#pragma unroll
    for (int i = 0; i < 4; ++i) {
      const int r = rg * 4 + i;
      if (r < nrows) {
        uint2 o = make_uint2(pack_bf2(acc[i][0], acc[i][1]),
                             pack_bf2(acc[i][2], acc[i][3]));
        reinterpret_cast<uint2*>(y + (size_t)(row0 + r) * 32)[cg] = o;
      }
    }
  }
}

// Merged dispatch: CSR pass-B (294 blocks) + layer-1 linear (1280 blocks).
// The build blocks leave >60% of CUs idle; linear-1 is independent of the CSR
// chain, so it fills them for free. Single union'd LDS buffer (34816 B).
__global__ __launch_bounds__(256) void build_lin_kernel(
    const int* __restrict__ bbase, const unsigned int* __restrict__ itemsU,
    const unsigned int* __restrict__ itemsE, int* __restrict__ offs,
    unsigned short* __restrict__ lists_u, int* __restrict__ lists_e,
    const float* __restrict__ xu, const float* __restrict__ Wu,
    const float* __restrict__ bu, unsigned int* __restrict__ yu,
    const float* __restrict__ xe, const float* __restrict__ We,
    const float* __restrict__ be, unsigned int* __restrict__ ye) {
  __shared__ __align__(16) unsigned char smem[64 * LDP * 2 * sizeof(float)];
  const int bx = blockIdx.x;
  if (bx < NBU) {
    build_user_body(smem, bbase, itemsU, offs, lists_u, bx);
  } else if (bx < NB) {
    build_event_body(smem, bbase, itemsE, offs, lists_e, bx - NBU);
  } else {
    const int bid = bx - NB;
    if (bid < LGU) {
      linear_tiles(smem, xu, Wu, bu, yu, NUM_USER, (NUM_USER + 63) / 64, bid, LGU);
    } else {
      linear_tiles(smem, xe, We, be, ye, NUM_EVENT, (NUM_EVENT + 63) / 64,
                   bid - LGU, LGE);
    }
  }
}

// Layer-2 linear (standalone, depends on gather-1 output).
__global__ __launch_bounds__(256) void linear_fused_kernel(
    const float* __restrict__ xu, const float* __restrict__ Wu,
    const float* __restrict__ bu, unsigned int* __restrict__ yu,
    const float* __restrict__ xe, const float* __restrict__ We,
    const float* __restrict__ be, unsigned int* __restrict__ ye) {
  __shared__ __align__(16) unsigned char smem[64 * LDP * 2 * sizeof(float)];
  if (blockIdx.x < LGU) {
    linear_tiles(smem, xu, Wu, bu, yu, NUM_USER, (NUM_USER + 63) / 64,
                 blockIdx.x, LGU);
  } else {
    linear_tiles(smem, xe, We, be, ye, NUM_EVENT, (NUM_EVENT + 63) / 64,
                 blockIdx.x - LGU, LGE);
  }
}

// ---------------- Fused gather aggregation (phase-sequential, prefetched) ----------------
// Eighth-wave (8 lanes) per node; lane dl holds dims 8dl..8dl+7 as one uint4.
// vs. the previous quarter-wave/uint2 layout: 2x node streams per wave (8
// instead of 4), and one row-load instruction now fetches a FULL 128 B row
// across the 8-lane group (8 rows per wave-instruction). Index loads are
// wave-uniform within a group (same address -> single request). Same per-dim
// accumulation order -> bit-identical results.
template <typename IdxT>
__device__ __forceinline__ void gather_phase(
    const int* __restrict__ offs, const IdxT* __restrict__ lists,
    const uint4* __restrict__ lin_self, const uint4* __restrict__ lin_other,
    float4* __restrict__ out, int n, int obase, int lbase, int stream_id,
    int nstreams, int dl) {
  int node = stream_id;
  if (node >= n) return;
  int g = obase + node;
  int start = (g == 0) ? 0 : offs[g - 1];
  int end = offs[g];
  uint4 sv = lin_self[(size_t)node * 8 + dl];

  while (true) {
    // Prefetch next node's descriptors (issued before the gather chain).
    const int nnode = node + nstreams;
    int nstart = 0, nend = 0;
    uint4 nsv = make_uint4(0u, 0u, 0u, 0u);
    if (nnode < n) {
      const int ng = obase + nnode;
      nstart = offs[ng - 1];
      nend = offs[ng];
      nsv = lin_self[(size_t)nnode * 8 + dl];
    }

    float a0 = bf_lo(sv.x), a1 = bf_hi(sv.x);
    float a2 = bf_lo(sv.y), a3 = bf_hi(sv.y);
    float a4 = bf_lo(sv.z), a5 = bf_hi(sv.z);
    float a6 = bf_lo(sv.w), a7 = bf_hi(sv.w);
    int j = start;
    for (; j + 4 <= end; j += 4) {
      int o[4];
#pragma unroll
      for (int t = 0; t < 4; ++t) o[t] = (int)lists[j + t - lbase];
      uint4 v[4];
#pragma unroll
      for (int t = 0; t < 4; ++t) v[t] = lin_other[(size_t)o[t] * 8 + dl];
#pragma unroll
      for (int t = 0; t < 4; ++t) {
        a0 += bf_lo(v[t].x); a1 += bf_hi(v[t].x);
        a2 += bf_lo(v[t].y); a3 += bf_hi(v[t].y);
        a4 += bf_lo(v[t].z); a5 += bf_hi(v[t].z);
        a6 += bf_lo(v[t].w); a7 += bf_hi(v[t].w);
      }
    }
    for (; j < end; ++j) {
      const int o0 = (int)lists[j - lbase];
      const uint4 v0 = lin_other[(size_t)o0 * 8 + dl];
      a0 += bf_lo(v0.x); a1 += bf_hi(v0.x);
      a2 += bf_lo(v0.y); a3 += bf_hi(v0.y);
      a4 += bf_lo(v0.z); a5 += bf_hi(v0.z);
      a6 += bf_lo(v0.w); a7 += bf_hi(v0.w);
    }
    const float inv = 1.0f / (float)(end - start + 1);
    out[(size_t)node * 16 + dl * 2] =
        make_float4(a0 * inv, a1 * inv, a2 * inv, a3 * inv);
    out[(size_t)node * 16 + dl * 2 + 1] =
        make_float4(a4 * inv, a5 * inv, a6 * inv, a7 * inv);

    if (nnode >= n) break;
    node = nnode;
    start = nstart;
    end = nend;
    sv = nsv;
  }
}

__global__ __launch_bounds__(256) void gather_fused_kernel(
    const int* __restrict__ offs, const unsigned short* __restrict__ lists_u,
    const int* __restrict__ lists_e, const unsigned int* __restrict__ lin_u,
    const unsigned int* __restrict__ lin_e, float* __restrict__ out_u,
    float* __restrict__ out_e) {
  const int lane = threadIdx.x & 63;
  const int dl = lane & 7;
  const int ew = ((blockIdx.x * (blockDim.x >> 6) + (threadIdx.x >> 6)) << 3) |
                 (lane >> 3);               // global eighth-wave id
  const int nstreams = GGRID * 32;          // 65536 streams, both phases
  gather_phase<unsigned short>(
      offs, lists_u, reinterpret_cast<const uint4*>(lin_u),
      reinterpret_cast<const uint4*>(lin_e), reinterpret_cast<float4*>(out_u),
      NUM_USER, 0, 0, ew, nstreams, dl);
  gather_phase<int>(
      offs, lists_e, reinterpret_cast<const uint4*>(lin_e),
      reinterpret_cast<const uint4*>(lin_u), reinterpret_cast<float4*>(out_e),
      NUM_EVENT, NUM_USER, NUM_EDGES, ew, nstreams, dl);
}

// ---------------- Launch ----------------

extern "C" void kernel_launch(void* const* d_in, const int* in_sizes, int n_in,
                              void* d_out, int out_size, void* d_ws,
                              size_t ws_size, hipStream_t stream) {
  const float* x_user = (const float*)d_in[0];
  const float* x_event = (const float*)d_in[1];
  const int* src = (const int*)d_in[2];
  const int* dst = (const int*)d_in[3];
  const float* Wu0 = (const float*)d_in[4];
  const float* bu0 = (const float*)d_in[5];
  const float* We0 = (const float*)d_in[6];
  const float* be0 = (const float*)d_in[7];
  const float* Wu1 = (const float*)d_in[8];
  const float* bu1 = (const float*)d_in[9];
  const float* We1 = (const float*)d_in[10];
  const float* be1 = (const float*)d_in[11];

  unsigned int* lin_u = (unsigned int*)d_ws;            // 6.4M u32
  unsigned int* lin_e = lin_u + (size_t)NUM_USER * 32;  // 1.6M u32
  int* offs = (int*)(lin_e + (size_t)NUM_EVENT * 32);   // 250,000
  int* bc = offs + (NUM_USER + NUM_EVENT);              // 294
  int* bbase = bc + NB;                                 // 295
  int* gcur = bbase + NB + 1;                           // 294
  unsigned int* itemsU = (unsigned int*)(gcur + NB);    // 1M
  unsigned int* itemsE = itemsU + NUM_EDGES;            // 1M
  int* lists_e = (int*)(itemsE + NUM_EDGES);            // 1M int
  unsigned short* lists_u = (unsigned short*)(lists_e + NUM_EDGES);  // 1M u16

  float* out_u = (float*)d_out;
  float* out_e = out_u + (size_t)NUM_USER * DDIM;

  // --- CSR build (bucketed counting sort; shared by both layers) ---
  hipMemsetAsync(bc, 0, NB * sizeof(int), stream);
  bucket_count_kernel<<<NCH, 256, 0, stream>>>(src, dst, bc);
  bucket_scan_kernel<<<1, 512, 0, stream>>>(bc, bbase, gcur);
  bucket_scatter_kernel<<<NCH, 256, 0, stream>>>(src, dst, gcur, itemsU, itemsE);

  // ---- CSR pass-B + Layer-1 linear (merged: independent work shares one grid) ----
  build_lin_kernel<<<NB + LGU + LGE, 256, 0, stream>>>(
      bbase, itemsU, itemsE, offs, lists_u, lists_e,
      x_user, Wu0, bu0, lin_u, x_event, We0, be0, lin_e);
  gather_fused_kernel<<<GGRID, 256, 0, stream>>>(
      offs, lists_u, lists_e, lin_u, lin_e, out_u, out_e);

  // ---- Layer 2 ----
  linear_fused_kernel<<<LGU + LGE, 256, 0, stream>>>(
      out_u, Wu1, bu1, lin_u, out_e, We1, be1, lin_e);
  gather_fused_kernel<<<GGRID, 256, 0, stream>>>(
      offs, lists_u, lists_e, lin_u, lin_e, out_u, out_e);
}